// Round 1
// baseline (803.981 us; speedup 1.0000x reference)
//
#include <hip/hip_runtime.h>
#include <math.h>

constexpr int CIN = 128, CHID = 64, COUT = 16;

// ---------------------------------------------------------------------------
// Edge-index dtype detection: if input is raw int64 (little-endian, values
// < 2^31), every odd int32 word is 0. If harness pre-converted to int32,
// odd words are random node ids (P[all 64 zero] ~ 0).
// ---------------------------------------------------------------------------
__global__ void detect_kernel(const int* __restrict__ e, int* __restrict__ flag) {
    int v = e[2 * threadIdx.x + 1];
    unsigned long long b = __ballot(v == 0);
    if (threadIdx.x == 0) flag[0] = (b == 0xFFFFFFFFFFFFFFFFULL) ? 1 : 0;
}

__global__ void convert_edges(const int* __restrict__ e, int E,
                              const int* __restrict__ flag,
                              int* __restrict__ srcI, int* __restrict__ dstI) {
    int is64 = flag[0];
    int stride = gridDim.x * blockDim.x;
    for (int t = blockIdx.x * blockDim.x + threadIdx.x; t < E; t += stride) {
        if (is64) { srcI[t] = e[2 * t]; dstI[t] = e[2 * (E + t)]; }
        else      { srcI[t] = e[t];     dstI[t] = e[E + t];       }
    }
}

// ---------------------------------------------------------------------------
// Dual-output GEMM: Da[n][0..OA) = X[n]·Wa[o] + bias[o] ; Db[n][0..OB) = X[n]·Wb[o]
// Weights LDS-staged transposed (k-major) -> conflict-free ds_read_b128.
// X tile LDS-staged row-major, rows padded to K+4 floats.
// Thread layout: og = tid % (O/4) owns 4 outputs, slot = tid / (O/4) owns T nodes.
// ---------------------------------------------------------------------------
template<int K, int OA, int OB, int NSLOT, int T>
__global__ __launch_bounds__(512)
void gemm_dual(const float* __restrict__ X, int N,
               const float* __restrict__ Wa, const float* __restrict__ Wb,
               const float* __restrict__ bias,
               float* __restrict__ Da, float* __restrict__ Db) {
    constexpr int O = OA + OB;
    constexpr int OG = O / 4;
    constexpr int TILE = NSLOT * T;
    constexpr int PADK = K + 4;
    constexpr int BLOCK = OG * NSLOT;
    static_assert(BLOCK == 512, "block size mismatch");

    __shared__ float wT[K * O];
    __shared__ float xs[TILE * PADK];
    const int tid = threadIdx.x;

    // stage Wa^T (cols [0,OA)) and Wb^T (cols [OA,O)) -- k-major
    for (int i4 = tid; i4 < OA * (K / 4); i4 += BLOCK) {
        int o = i4 % OA, kq = i4 / OA;
        float4 v = *(const float4*)&Wa[o * K + kq * 4];
        wT[(4 * kq + 0) * O + o] = v.x;
        wT[(4 * kq + 1) * O + o] = v.y;
        wT[(4 * kq + 2) * O + o] = v.z;
        wT[(4 * kq + 3) * O + o] = v.w;
    }
    for (int i4 = tid; i4 < OB * (K / 4); i4 += BLOCK) {
        int o = i4 % OB, kq = i4 / OB;
        float4 v = *(const float4*)&Wb[o * K + kq * 4];
        wT[(4 * kq + 0) * O + OA + o] = v.x;
        wT[(4 * kq + 1) * O + OA + o] = v.y;
        wT[(4 * kq + 2) * O + OA + o] = v.z;
        wT[(4 * kq + 3) * O + OA + o] = v.w;
    }

    const int og = tid % OG;
    const int slot = tid / OG;
    const int o4 = og * 4;
    float4 bv = make_float4(0.f, 0.f, 0.f, 0.f);
    if (o4 < OA) bv = *(const float4*)&bias[o4];

    const int n0 = blockIdx.x * TILE;

    // stage x tile (coalesced float4 loads)
    for (int i4 = tid; i4 < TILE * (K / 4); i4 += BLOCK) {
        int node = i4 / (K / 4), kq = i4 % (K / 4);
        int n = n0 + node;
        float4 v = make_float4(0.f, 0.f, 0.f, 0.f);
        if (n < N) v = *(const float4*)&X[(size_t)n * K + kq * 4];
        *(float4*)&xs[node * PADK + kq * 4] = v;
    }
    __syncthreads();

    float4 acc[T];
#pragma unroll
    for (int i = 0; i < T; ++i) acc[i] = make_float4(0.f, 0.f, 0.f, 0.f);

    const float* xrow = &xs[slot * T * PADK];
#pragma unroll 4
    for (int k = 0; k < K; ++k) {
        float4 w4 = *(const float4*)&wT[k * O + o4];
#pragma unroll
        for (int i = 0; i < T; ++i) {
            float xv = xrow[i * PADK + k];
            acc[i].x = fmaf(xv, w4.x, acc[i].x);
            acc[i].y = fmaf(xv, w4.y, acc[i].y);
            acc[i].z = fmaf(xv, w4.z, acc[i].z);
            acc[i].w = fmaf(xv, w4.w, acc[i].w);
        }
    }

#pragma unroll
    for (int i = 0; i < T; ++i) {
        int n = n0 + slot * T + i;
        if (n >= N) continue;
        float4 r = acc[i];
        if (o4 < OA) {
            r.x += bv.x; r.y += bv.y; r.z += bv.z; r.w += bv.w;
            *(float4*)&Da[(size_t)n * OA + o4] = r;
        } else {
            *(float4*)&Db[(size_t)n * OB + (o4 - OA)] = r;
        }
    }
}

// ---------------------------------------------------------------------------
// Scatter-add: D[dst[e]] += S[src[e]], rows of F floats, float4 gather +
// 4 scalar f32 atomics per thread.
// ---------------------------------------------------------------------------
template<int F>
__global__ void scatter_add(const int* __restrict__ srcI, const int* __restrict__ dstI,
                            int E, const float* __restrict__ S, float* __restrict__ D) {
    constexpr int Q = F / 4;
    const int total = E * Q;
    const int stride = gridDim.x * blockDim.x;
    for (int idx = blockIdx.x * blockDim.x + threadIdx.x; idx < total; idx += stride) {
        int e = idx / Q, q = idx % Q;
        int s = srcI[e], d = dstI[e];
        float4 v = *(const float4*)&S[(size_t)s * F + q * 4];
        float* p = &D[(size_t)d * F + q * 4];
        atomicAdd(p + 0, v.x);
        atomicAdd(p + 1, v.y);
        atomicAdd(p + 2, v.z);
        atomicAdd(p + 3, v.w);
    }
}

// A = relu(A + C), elementwise float4
__global__ void relu_add(float* __restrict__ A, const float* __restrict__ C, int n4) {
    const int stride = gridDim.x * blockDim.x;
    for (int i = blockIdx.x * blockDim.x + threadIdx.x; i < n4; i += stride) {
        float4 a = ((const float4*)A)[i];
        float4 c = ((const float4*)C)[i];
        a.x = fmaxf(a.x + c.x, 0.f);
        a.y = fmaxf(a.y + c.y, 0.f);
        a.z = fmaxf(a.z + c.z, 0.f);
        a.w = fmaxf(a.w + c.w, 0.f);
        ((float4*)A)[i] = a;
    }
}

// out[n] = log_softmax(t3[n] + g2[n]) over 16 features; 16 lanes per row
__global__ void logsoftmax16(const float* __restrict__ t3, const float* __restrict__ g2,
                             float* __restrict__ out, int N) {
    int tid = blockIdx.x * blockDim.x + threadIdx.x;
    int n = tid / 16, f = tid % 16;
    if (n >= N) return;
    float v = t3[n * 16 + f] + g2[n * 16 + f];
    float m = v;
    for (int d = 1; d < 16; d <<= 1) m = fmaxf(m, __shfl_xor(m, d, 16));
    float ev = expf(v - m);
    float s = ev;
    for (int d = 1; d < 16; d <<= 1) s += __shfl_xor(s, d, 16);
    out[n * 16 + f] = (v - m) - logf(s);
}

extern "C" void kernel_launch(void* const* d_in, const int* in_sizes, int n_in,
                              void* d_out, int out_size, void* d_ws, size_t ws_size,
                              hipStream_t stream) {
    const float* X      = (const float*)d_in[0];
    const int*   EIDX   = (const int*)d_in[1];
    const float* W1REL  = (const float*)d_in[2];
    const float* W1ROOT = (const float*)d_in[3];
    const float* B1     = (const float*)d_in[4];
    const float* W2REL  = (const float*)d_in[5];
    const float* W2ROOT = (const float*)d_in[6];
    const float* B2     = (const float*)d_in[7];
    float* OUT = (float*)d_out;

    const int N = in_sizes[0] / CIN;   // 100000
    const int E = in_sizes[1] / 2;     // 640000

    size_t need = 256 + (size_t)2 * E * 4 + (size_t)N * (3 * CHID + COUT) * 4;
    if (ws_size < need) return;  // workspace too small; bail (will fail validation loudly)

    char* wsb = (char*)d_ws;
    int* flag = (int*)wsb;
    int* srcI = (int*)(wsb + 256);
    int* dstI = srcI + E;
    float* A  = (float*)(wsb + 256 + (size_t)2 * E * 4); // t0 -> h     [N,64]
    float* Bt = A + (size_t)N * CHID;                    // t1 -> t3|t2 [N,64]
    float* C  = Bt + (size_t)N * CHID;                   // agg1        [N,64]
    float* G2 = C + (size_t)N * CHID;                    // agg2        [N,16]
    float* T3 = Bt;                                      // [N,16]
    float* T2 = Bt + (size_t)N * COUT;                   // [N,16]

    hipMemsetAsync(C,  0, (size_t)N * CHID * 4, stream);
    hipMemsetAsync(G2, 0, (size_t)N * COUT * 4, stream);

    detect_kernel<<<1, 64, 0, stream>>>(EIDX, flag);
    convert_edges<<<1024, 256, 0, stream>>>(EIDX, E, flag, srcI, dstI);

    // layer 1: X[N,128] -> A = X@W1root^T + b1, Bt = X@W1rel^T
    {
        constexpr int TILE = 16 * 6;  // NSLOT=16, T=6
        int grid = (N + TILE - 1) / TILE;
        gemm_dual<128, 64, 64, 16, 6><<<grid, 512, 0, stream>>>(X, N, W1ROOT, W1REL, B1, A, Bt);
    }

    scatter_add<64><<<4096, 256, 0, stream>>>(srcI, dstI, E, Bt, C);
    relu_add<<<2048, 256, 0, stream>>>(A, C, N * CHID / 4);

    // layer 2: A[N,64] -> T3 = A@W2root^T + b2, T2 = A@W2rel^T
    {
        constexpr int TILE = 64 * 4;  // NSLOT=64, T=4
        int grid = (N + TILE - 1) / TILE;
        gemm_dual<64, 16, 16, 64, 4><<<grid, 512, 0, stream>>>(A, N, W2ROOT, W2REL, B2, T3, T2);
    }

    scatter_add<16><<<2048, 256, 0, stream>>>(srcI, dstI, E, T2, G2);
    logsoftmax16<<<(N * 16 + 255) / 256, 256, 0, stream>>>(T3, G2, OUT, N);
}

// Round 2
// 443.458 us; speedup vs baseline: 1.8130x; 1.8130x over previous
//
#include <hip/hip_runtime.h>
#include <math.h>

constexpr int CIN = 128, CHID = 64, COUT = 16;

// ---------------------------------------------------------------------------
// Edge-index dtype detection: if input is raw int64 (little-endian, values
// < 2^31), every odd int32 word is 0.
// ---------------------------------------------------------------------------
__global__ void detect_kernel(const int* __restrict__ e, int* __restrict__ flag) {
    int v = e[2 * threadIdx.x + 1];
    unsigned long long b = __ballot(v == 0);
    if (threadIdx.x == 0) flag[0] = (b == 0xFFFFFFFFFFFFFFFFULL) ? 1 : 0;
}

// convert to int32 src/dst + histogram of dst (int atomics)
__global__ void convert_hist(const int* __restrict__ e, int E,
                             const int* __restrict__ flag,
                             int* __restrict__ srcI, int* __restrict__ dstI,
                             int* __restrict__ counts) {
    int is64 = flag[0];
    int stride = gridDim.x * blockDim.x;
    for (int t = blockIdx.x * blockDim.x + threadIdx.x; t < E; t += stride) {
        int s, d;
        if (is64) { s = e[2 * t]; d = e[2 * (E + t)]; }
        else      { s = e[t];     d = e[E + t];       }
        srcI[t] = s;
        dstI[t] = d;
        atomicAdd(&counts[d], 1);
    }
}

// single-block exclusive scan of counts[N] -> rowptr[N+1], duplicate to cursor
__global__ __launch_bounds__(1024)
void scan_kernel(const int* __restrict__ counts, int N,
                 int* __restrict__ rowptr, int* __restrict__ cursor) {
    __shared__ int part[1024];
    const int tid = threadIdx.x;
    const int chunk = (N + 1023) / 1024;
    const int lo = tid * chunk;
    const int hi = min(lo + chunk, N);
    int s = 0;
    for (int i = lo; i < hi; ++i) s += counts[i];
    part[tid] = s;
    __syncthreads();
    // Hillis-Steele inclusive scan over 1024 partials
    for (int d = 1; d < 1024; d <<= 1) {
        int v = (tid >= d) ? part[tid - d] : 0;
        __syncthreads();
        part[tid] += v;
        __syncthreads();
    }
    int prefix = (tid == 0) ? 0 : part[tid - 1];
    for (int i = lo; i < hi; ++i) {
        rowptr[i] = prefix;
        cursor[i] = prefix;
        prefix += counts[i];
    }
    if (tid == 1023) rowptr[N] = part[1023];
}

// bucket-fill: edgesrc grouped by dst
__global__ void fill_kernel(const int* __restrict__ srcI, const int* __restrict__ dstI,
                            int E, int* __restrict__ cursor, int* __restrict__ edgesrc) {
    int stride = gridDim.x * blockDim.x;
    for (int t = blockIdx.x * blockDim.x + threadIdx.x; t < E; t += stride) {
        int p = atomicAdd(&cursor[dstI[t]], 1);
        edgesrc[p] = srcI[t];
    }
}

// ---------------------------------------------------------------------------
// Dual-output GEMM (unchanged from R1): Da = X·Wa^T + bias ; Db = X·Wb^T
// ---------------------------------------------------------------------------
template<int K, int OA, int OB, int NSLOT, int T>
__global__ __launch_bounds__(512)
void gemm_dual(const float* __restrict__ X, int N,
               const float* __restrict__ Wa, const float* __restrict__ Wb,
               const float* __restrict__ bias,
               float* __restrict__ Da, float* __restrict__ Db) {
    constexpr int O = OA + OB;
    constexpr int OG = O / 4;
    constexpr int TILE = NSLOT * T;
    constexpr int PADK = K + 4;
    constexpr int BLOCK = OG * NSLOT;
    static_assert(BLOCK == 512, "block size mismatch");

    __shared__ float wT[K * O];
    __shared__ float xs[TILE * PADK];
    const int tid = threadIdx.x;

    for (int i4 = tid; i4 < OA * (K / 4); i4 += BLOCK) {
        int o = i4 % OA, kq = i4 / OA;
        float4 v = *(const float4*)&Wa[o * K + kq * 4];
        wT[(4 * kq + 0) * O + o] = v.x;
        wT[(4 * kq + 1) * O + o] = v.y;
        wT[(4 * kq + 2) * O + o] = v.z;
        wT[(4 * kq + 3) * O + o] = v.w;
    }
    for (int i4 = tid; i4 < OB * (K / 4); i4 += BLOCK) {
        int o = i4 % OB, kq = i4 / OB;
        float4 v = *(const float4*)&Wb[o * K + kq * 4];
        wT[(4 * kq + 0) * O + OA + o] = v.x;
        wT[(4 * kq + 1) * O + OA + o] = v.y;
        wT[(4 * kq + 2) * O + OA + o] = v.z;
        wT[(4 * kq + 3) * O + OA + o] = v.w;
    }

    const int og = tid % OG;
    const int slot = tid / OG;
    const int o4 = og * 4;
    float4 bv = make_float4(0.f, 0.f, 0.f, 0.f);
    if (o4 < OA) bv = *(const float4*)&bias[o4];

    const int n0 = blockIdx.x * TILE;

    for (int i4 = tid; i4 < TILE * (K / 4); i4 += BLOCK) {
        int node = i4 / (K / 4), kq = i4 % (K / 4);
        int n = n0 + node;
        float4 v = make_float4(0.f, 0.f, 0.f, 0.f);
        if (n < N) v = *(const float4*)&X[(size_t)n * K + kq * 4];
        *(float4*)&xs[node * PADK + kq * 4] = v;
    }
    __syncthreads();

    float4 acc[T];
#pragma unroll
    for (int i = 0; i < T; ++i) acc[i] = make_float4(0.f, 0.f, 0.f, 0.f);

    const float* xrow = &xs[slot * T * PADK];
#pragma unroll 4
    for (int k = 0; k < K; ++k) {
        float4 w4 = *(const float4*)&wT[k * O + o4];
#pragma unroll
        for (int i = 0; i < T; ++i) {
            float xv = xrow[i * PADK + k];
            acc[i].x = fmaf(xv, w4.x, acc[i].x);
            acc[i].y = fmaf(xv, w4.y, acc[i].y);
            acc[i].z = fmaf(xv, w4.z, acc[i].z);
            acc[i].w = fmaf(xv, w4.w, acc[i].w);
        }
    }

#pragma unroll
    for (int i = 0; i < T; ++i) {
        int n = n0 + slot * T + i;
        if (n >= N) continue;
        float4 r = acc[i];
        if (o4 < OA) {
            r.x += bv.x; r.y += bv.y; r.z += bv.z; r.w += bv.w;
            *(float4*)&Da[(size_t)n * OA + o4] = r;
        } else {
            *(float4*)&Db[(size_t)n * OB + (o4 - OA)] = r;
        }
    }
}

// ---------------------------------------------------------------------------
// CSR gather + fused relu(t0 + agg), in place over A.
// Thread (n, q) sums quad q of t1 rows of n's in-neighbors.
// ---------------------------------------------------------------------------
__global__ void gather_relu64(const int* __restrict__ rowptr, const int* __restrict__ edgesrc,
                              const float* __restrict__ T1, float* __restrict__ A, int N) {
    constexpr int F = 64, Q = F / 4;
    int idx = blockIdx.x * blockDim.x + threadIdx.x;
    int n = idx / Q, q = idx % Q;
    if (n >= N) return;
    int beg = rowptr[n], end = rowptr[n + 1];
    float4 acc = make_float4(0.f, 0.f, 0.f, 0.f);
    for (int j = beg; j < end; ++j) {
        int s = edgesrc[j];
        float4 v = *(const float4*)&T1[(size_t)s * F + q * 4];
        acc.x += v.x; acc.y += v.y; acc.z += v.z; acc.w += v.w;
    }
    float4 a = *(const float4*)&A[(size_t)n * F + q * 4];
    a.x = fmaxf(a.x + acc.x, 0.f);
    a.y = fmaxf(a.y + acc.y, 0.f);
    a.z = fmaxf(a.z + acc.z, 0.f);
    a.w = fmaxf(a.w + acc.w, 0.f);
    *(float4*)&A[(size_t)n * F + q * 4] = a;
}

// ---------------------------------------------------------------------------
// CSR gather of t2 (width 16) + fused log_softmax(t3 + agg).
// 4 threads per node, each owns a quad; reductions via width-4 shfl_xor.
// ---------------------------------------------------------------------------
__global__ void gather_lsm(const int* __restrict__ rowptr, const int* __restrict__ edgesrc,
                           const float* __restrict__ T3, const float* __restrict__ T2,
                           float* __restrict__ out, int N) {
    int idx = blockIdx.x * blockDim.x + threadIdx.x;
    int n = idx / 4, c = idx % 4;
    if (n >= N) return;
    int beg = rowptr[n], end = rowptr[n + 1];
    float4 acc = make_float4(0.f, 0.f, 0.f, 0.f);
    for (int j = beg; j < end; ++j) {
        int s = edgesrc[j];
        float4 v = *(const float4*)&T2[(size_t)s * 16 + c * 4];
        acc.x += v.x; acc.y += v.y; acc.z += v.z; acc.w += v.w;
    }
    float4 t = *(const float4*)&T3[(size_t)n * 16 + c * 4];
    float4 v = make_float4(t.x + acc.x, t.y + acc.y, t.z + acc.z, t.w + acc.w);
    float m = fmaxf(fmaxf(v.x, v.y), fmaxf(v.z, v.w));
    for (int d = 1; d < 4; d <<= 1) m = fmaxf(m, __shfl_xor(m, d, 4));
    float s = expf(v.x - m) + expf(v.y - m) + expf(v.z - m) + expf(v.w - m);
    for (int d = 1; d < 4; d <<= 1) s += __shfl_xor(s, d, 4);
    float ls = m + logf(s);
    float4 r = make_float4(v.x - ls, v.y - ls, v.z - ls, v.w - ls);
    *(float4*)&out[(size_t)n * 16 + c * 4] = r;
}

extern "C" void kernel_launch(void* const* d_in, const int* in_sizes, int n_in,
                              void* d_out, int out_size, void* d_ws, size_t ws_size,
                              hipStream_t stream) {
    const float* X      = (const float*)d_in[0];
    const int*   EIDX   = (const int*)d_in[1];
    const float* W1REL  = (const float*)d_in[2];
    const float* W1ROOT = (const float*)d_in[3];
    const float* B1     = (const float*)d_in[4];
    const float* W2REL  = (const float*)d_in[5];
    const float* W2ROOT = (const float*)d_in[6];
    const float* B2     = (const float*)d_in[7];
    float* OUT = (float*)d_out;

    const int N = in_sizes[0] / CIN;   // 100000
    const int E = in_sizes[1] / 2;     // 640000

    char* wsb = (char*)d_ws;
    size_t off = 0;
    auto alloc = [&](size_t bytes) { void* p = wsb + off; off += (bytes + 255) & ~size_t(255); return p; };

    int* flag    = (int*)alloc(256);
    int* srcI    = (int*)alloc((size_t)E * 4);
    int* dstI    = (int*)alloc((size_t)E * 4);
    int* edgesrc = (int*)alloc((size_t)E * 4);
    int* counts  = (int*)alloc((size_t)N * 4);
    int* rowptr  = (int*)alloc((size_t)(N + 1) * 4);
    int* cursor  = (int*)alloc((size_t)N * 4);
    float* A     = (float*)alloc((size_t)N * CHID * 4);  // t0 -> h (in place)
    float* Bt    = (float*)alloc((size_t)N * CHID * 4);  // t1, then t3|t2
    if (off > ws_size) return;

    float* T3 = Bt;                      // [N,16]
    float* T2 = Bt + (size_t)N * COUT;   // [N,16]

    hipMemsetAsync(counts, 0, (size_t)N * 4, stream);

    detect_kernel<<<1, 64, 0, stream>>>(EIDX, flag);
    convert_hist<<<1024, 256, 0, stream>>>(EIDX, E, flag, srcI, dstI, counts);
    scan_kernel<<<1, 1024, 0, stream>>>(counts, N, rowptr, cursor);
    fill_kernel<<<1024, 256, 0, stream>>>(srcI, dstI, E, cursor, edgesrc);

    // layer 1: A = X@W1root^T + b1, Bt = X@W1rel^T
    {
        constexpr int TILE = 16 * 6;
        int grid = (N + TILE - 1) / TILE;
        gemm_dual<128, 64, 64, 16, 6><<<grid, 512, 0, stream>>>(X, N, W1ROOT, W1REL, B1, A, Bt);
    }

    // h = relu(t0 + gather(t1))  [in place over A]
    {
        int threads = N * 16;
        gather_relu64<<<(threads + 255) / 256, 256, 0, stream>>>(rowptr, edgesrc, Bt, A, N);
    }

    // layer 2: T3 = h@W2root^T + b2, T2 = h@W2rel^T
    {
        constexpr int TILE = 64 * 4;
        int grid = (N + TILE - 1) / TILE;
        gemm_dual<64, 16, 16, 64, 4><<<grid, 512, 0, stream>>>(A, N, W2ROOT, W2REL, B2, T3, T2);
    }

    // out = log_softmax(t3 + gather(t2))
    {
        int threads = N * 4;
        gather_lsm<<<(threads + 255) / 256, 256, 0, stream>>>(rowptr, edgesrc, T3, T2, OUT, N);
    }
}

// Round 3
// 223.516 us; speedup vs baseline: 3.5970x; 1.9840x over previous
//
#include <hip/hip_runtime.h>
#include <math.h>

constexpr int CIN = 128, CHID = 64, COUT = 16;

// ---------------------------------------------------------------------------
// Edge-index dtype detection: if input is raw int64 (little-endian, values
// < 2^31), every odd int32 word is 0.
// ---------------------------------------------------------------------------
__global__ void detect_kernel(const int* __restrict__ e, int* __restrict__ flag) {
    int v = e[2 * threadIdx.x + 1];
    unsigned long long b = __ballot(v == 0);
    if (threadIdx.x == 0) flag[0] = (b == 0xFFFFFFFFFFFFFFFFULL) ? 1 : 0;
}

// convert to int32 src/dst + histogram of dst (int atomics)
__global__ void convert_hist(const int* __restrict__ e, int E,
                             const int* __restrict__ flag,
                             int* __restrict__ srcI, int* __restrict__ dstI,
                             int* __restrict__ counts) {
    int is64 = flag[0];
    int stride = gridDim.x * blockDim.x;
    for (int t = blockIdx.x * blockDim.x + threadIdx.x; t < E; t += stride) {
        int s, d;
        if (is64) { s = e[2 * t]; d = e[2 * (E + t)]; }
        else      { s = e[t];     d = e[E + t];       }
        srcI[t] = s;
        dstI[t] = d;
        atomicAdd(&counts[d], 1);
    }
}

// ---------------------------------------------------------------------------
// Multi-block exclusive scan of counts[N] -> rowptr[N+1] (+ cursor copy).
// Pass A: per-block (1024-elem) partial sums. Pass B: scan of block sums
// (single small block). Pass C: per-block scan + apply offset.
// ---------------------------------------------------------------------------
__global__ __launch_bounds__(256)
void scan_partials(const int* __restrict__ counts, int N, int* __restrict__ blocksum) {
    __shared__ int red[256];
    const int tid = threadIdx.x;
    const int base = blockIdx.x * 1024 + tid * 4;
    int s = 0;
#pragma unroll
    for (int i = 0; i < 4; ++i) {
        int idx = base + i;
        if (idx < N) s += counts[idx];
    }
    red[tid] = s;
    __syncthreads();
    for (int d = 128; d > 0; d >>= 1) {
        if (tid < d) red[tid] += red[tid + d];
        __syncthreads();
    }
    if (tid == 0) blocksum[blockIdx.x] = red[0];
}

__global__ __launch_bounds__(1024)
void scan_blocksums(const int* __restrict__ blocksum, int NB, int* __restrict__ blockoff) {
    __shared__ int part[1024];
    const int tid = threadIdx.x;
    part[tid] = (tid < NB) ? blocksum[tid] : 0;
    __syncthreads();
    for (int d = 1; d < 1024; d <<= 1) {
        int v = (tid >= d) ? part[tid - d] : 0;
        __syncthreads();
        part[tid] += v;
        __syncthreads();
    }
    if (tid < NB) blockoff[tid] = (tid == 0) ? 0 : part[tid - 1];
}

__global__ __launch_bounds__(256)
void scan_apply(const int* __restrict__ counts, int N, const int* __restrict__ blockoff,
                int* __restrict__ rowptr, int* __restrict__ cursor) {
    __shared__ int part[256];
    const int tid = threadIdx.x;
    const int base = blockIdx.x * 1024 + tid * 4;
    int c[4];
    int s = 0;
#pragma unroll
    for (int i = 0; i < 4; ++i) {
        int idx = base + i;
        c[i] = (idx < N) ? counts[idx] : 0;
        s += c[i];
    }
    part[tid] = s;
    __syncthreads();
    for (int d = 1; d < 256; d <<= 1) {
        int v = (tid >= d) ? part[tid - d] : 0;
        __syncthreads();
        part[tid] += v;
        __syncthreads();
    }
    int prefix = blockoff[blockIdx.x] + ((tid == 0) ? 0 : part[tid - 1]);
#pragma unroll
    for (int i = 0; i < 4; ++i) {
        int idx = base + i;
        if (idx < N) {
            rowptr[idx] = prefix;
            cursor[idx] = prefix;
            prefix += c[i];
            if (idx == N - 1) rowptr[N] = prefix;
        }
    }
}

// bucket-fill: edgesrc grouped by dst
__global__ void fill_kernel(const int* __restrict__ srcI, const int* __restrict__ dstI,
                            int E, int* __restrict__ cursor, int* __restrict__ edgesrc) {
    int stride = gridDim.x * blockDim.x;
    for (int t = blockIdx.x * blockDim.x + threadIdx.x; t < E; t += stride) {
        int p = atomicAdd(&cursor[dstI[t]], 1);
        edgesrc[p] = srcI[t];
    }
}

// ---------------------------------------------------------------------------
// Dual-output GEMM: Da = X·Wa^T + bias ; Db = X·Wb^T
// ---------------------------------------------------------------------------
template<int K, int OA, int OB, int NSLOT, int T>
__global__ __launch_bounds__(512)
void gemm_dual(const float* __restrict__ X, int N,
               const float* __restrict__ Wa, const float* __restrict__ Wb,
               const float* __restrict__ bias,
               float* __restrict__ Da, float* __restrict__ Db) {
    constexpr int O = OA + OB;
    constexpr int OG = O / 4;
    constexpr int TILE = NSLOT * T;
    constexpr int PADK = K + 4;
    constexpr int BLOCK = OG * NSLOT;
    static_assert(BLOCK == 512, "block size mismatch");

    __shared__ float wT[K * O];
    __shared__ float xs[TILE * PADK];
    const int tid = threadIdx.x;

    for (int i4 = tid; i4 < OA * (K / 4); i4 += BLOCK) {
        int o = i4 % OA, kq = i4 / OA;
        float4 v = *(const float4*)&Wa[o * K + kq * 4];
        wT[(4 * kq + 0) * O + o] = v.x;
        wT[(4 * kq + 1) * O + o] = v.y;
        wT[(4 * kq + 2) * O + o] = v.z;
        wT[(4 * kq + 3) * O + o] = v.w;
    }
    for (int i4 = tid; i4 < OB * (K / 4); i4 += BLOCK) {
        int o = i4 % OB, kq = i4 / OB;
        float4 v = *(const float4*)&Wb[o * K + kq * 4];
        wT[(4 * kq + 0) * O + OA + o] = v.x;
        wT[(4 * kq + 1) * O + OA + o] = v.y;
        wT[(4 * kq + 2) * O + OA + o] = v.z;
        wT[(4 * kq + 3) * O + OA + o] = v.w;
    }

    const int og = tid % OG;
    const int slot = tid / OG;
    const int o4 = og * 4;
    float4 bv = make_float4(0.f, 0.f, 0.f, 0.f);
    if (o4 < OA) bv = *(const float4*)&bias[o4];

    const int n0 = blockIdx.x * TILE;

    for (int i4 = tid; i4 < TILE * (K / 4); i4 += BLOCK) {
        int node = i4 / (K / 4), kq = i4 % (K / 4);
        int n = n0 + node;
        float4 v = make_float4(0.f, 0.f, 0.f, 0.f);
        if (n < N) v = *(const float4*)&X[(size_t)n * K + kq * 4];
        *(float4*)&xs[node * PADK + kq * 4] = v;
    }
    __syncthreads();

    float4 acc[T];
#pragma unroll
    for (int i = 0; i < T; ++i) acc[i] = make_float4(0.f, 0.f, 0.f, 0.f);

    const float* xrow = &xs[slot * T * PADK];
#pragma unroll 4
    for (int k = 0; k < K; ++k) {
        float4 w4 = *(const float4*)&wT[k * O + o4];
#pragma unroll
        for (int i = 0; i < T; ++i) {
            float xv = xrow[i * PADK + k];
            acc[i].x = fmaf(xv, w4.x, acc[i].x);
            acc[i].y = fmaf(xv, w4.y, acc[i].y);
            acc[i].z = fmaf(xv, w4.z, acc[i].z);
            acc[i].w = fmaf(xv, w4.w, acc[i].w);
        }
    }

#pragma unroll
    for (int i = 0; i < T; ++i) {
        int n = n0 + slot * T + i;
        if (n >= N) continue;
        float4 r = acc[i];
        if (o4 < OA) {
            r.x += bv.x; r.y += bv.y; r.z += bv.z; r.w += bv.w;
            *(float4*)&Da[(size_t)n * OA + o4] = r;
        } else {
            *(float4*)&Db[(size_t)n * OB + (o4 - OA)] = r;
        }
    }
}

// ---------------------------------------------------------------------------
// CSR gather + fused relu(t0 + agg), in place over A.
// ---------------------------------------------------------------------------
__global__ void gather_relu64(const int* __restrict__ rowptr, const int* __restrict__ edgesrc,
                              const float* __restrict__ T1, float* __restrict__ A, int N) {
    constexpr int F = 64, Q = F / 4;
    int idx = blockIdx.x * blockDim.x + threadIdx.x;
    int n = idx / Q, q = idx % Q;
    if (n >= N) return;
    int beg = rowptr[n], end = rowptr[n + 1];
    float4 acc = make_float4(0.f, 0.f, 0.f, 0.f);
    for (int j = beg; j < end; ++j) {
        int s = edgesrc[j];
        float4 v = *(const float4*)&T1[(size_t)s * F + q * 4];
        acc.x += v.x; acc.y += v.y; acc.z += v.z; acc.w += v.w;
    }
    float4 a = *(const float4*)&A[(size_t)n * F + q * 4];
    a.x = fmaxf(a.x + acc.x, 0.f);
    a.y = fmaxf(a.y + acc.y, 0.f);
    a.z = fmaxf(a.z + acc.z, 0.f);
    a.w = fmaxf(a.w + acc.w, 0.f);
    *(float4*)&A[(size_t)n * F + q * 4] = a;
}

// ---------------------------------------------------------------------------
// CSR gather of t2 (width 16) + fused log_softmax(t3 + agg).
// ---------------------------------------------------------------------------
__global__ void gather_lsm(const int* __restrict__ rowptr, const int* __restrict__ edgesrc,
                           const float* __restrict__ T3, const float* __restrict__ T2,
                           float* __restrict__ out, int N) {
    int idx = blockIdx.x * blockDim.x + threadIdx.x;
    int n = idx / 4, c = idx % 4;
    if (n >= N) return;
    int beg = rowptr[n], end = rowptr[n + 1];
    float4 acc = make_float4(0.f, 0.f, 0.f, 0.f);
    for (int j = beg; j < end; ++j) {
        int s = edgesrc[j];
        float4 v = *(const float4*)&T2[(size_t)s * 16 + c * 4];
        acc.x += v.x; acc.y += v.y; acc.z += v.z; acc.w += v.w;
    }
    float4 t = *(const float4*)&T3[(size_t)n * 16 + c * 4];
    float4 v = make_float4(t.x + acc.x, t.y + acc.y, t.z + acc.z, t.w + acc.w);
    float m = fmaxf(fmaxf(v.x, v.y), fmaxf(v.z, v.w));
    for (int d = 1; d < 4; d <<= 1) m = fmaxf(m, __shfl_xor(m, d, 4));
    float s = expf(v.x - m) + expf(v.y - m) + expf(v.z - m) + expf(v.w - m);
    for (int d = 1; d < 4; d <<= 1) s += __shfl_xor(s, d, 4);
    float ls = m + logf(s);
    float4 r = make_float4(v.x - ls, v.y - ls, v.z - ls, v.w - ls);
    *(float4*)&out[(size_t)n * 16 + c * 4] = r;
}

extern "C" void kernel_launch(void* const* d_in, const int* in_sizes, int n_in,
                              void* d_out, int out_size, void* d_ws, size_t ws_size,
                              hipStream_t stream) {
    const float* X      = (const float*)d_in[0];
    const int*   EIDX   = (const int*)d_in[1];
    const float* W1REL  = (const float*)d_in[2];
    const float* W1ROOT = (const float*)d_in[3];
    const float* B1     = (const float*)d_in[4];
    const float* W2REL  = (const float*)d_in[5];
    const float* W2ROOT = (const float*)d_in[6];
    const float* B2     = (const float*)d_in[7];
    float* OUT = (float*)d_out;

    const int N = in_sizes[0] / CIN;   // 100000
    const int E = in_sizes[1] / 2;     // 640000
    const int NB = (N + 1023) / 1024;  // scan blocks (98 for N=100000)

    char* wsb = (char*)d_ws;
    size_t off = 0;
    auto alloc = [&](size_t bytes) { void* p = wsb + off; off += (bytes + 255) & ~size_t(255); return p; };

    int* flag     = (int*)alloc(256);
    int* srcI     = (int*)alloc((size_t)E * 4);
    int* dstI     = (int*)alloc((size_t)E * 4);
    int* edgesrc  = (int*)alloc((size_t)E * 4);
    int* counts   = (int*)alloc((size_t)N * 4);
    int* rowptr   = (int*)alloc((size_t)(N + 1) * 4);
    int* cursor   = (int*)alloc((size_t)N * 4);
    int* blocksum = (int*)alloc((size_t)NB * 4);
    int* blockoff = (int*)alloc((size_t)NB * 4);
    float* A      = (float*)alloc((size_t)N * CHID * 4);  // t0 -> h (in place)
    float* Bt     = (float*)alloc((size_t)N * CHID * 4);  // t1, then t3|t2
    if (off > ws_size) return;

    float* T3 = Bt;                      // [N,16]
    float* T2 = Bt + (size_t)N * COUT;   // [N,16]

    hipMemsetAsync(counts, 0, (size_t)N * 4, stream);

    detect_kernel<<<1, 64, 0, stream>>>(EIDX, flag);
    convert_hist<<<1024, 256, 0, stream>>>(EIDX, E, flag, srcI, dstI, counts);
    scan_partials<<<NB, 256, 0, stream>>>(counts, N, blocksum);
    scan_blocksums<<<1, 1024, 0, stream>>>(blocksum, NB, blockoff);
    scan_apply<<<NB, 256, 0, stream>>>(counts, N, blockoff, rowptr, cursor);
    fill_kernel<<<1024, 256, 0, stream>>>(srcI, dstI, E, cursor, edgesrc);

    // layer 1: A = X@W1root^T + b1, Bt = X@W1rel^T
    {
        constexpr int TILE = 16 * 6;
        int grid = (N + TILE - 1) / TILE;
        gemm_dual<128, 64, 64, 16, 6><<<grid, 512, 0, stream>>>(X, N, W1ROOT, W1REL, B1, A, Bt);
    }

    // h = relu(t0 + gather(t1))  [in place over A]
    {
        int threads = N * 16;
        gather_relu64<<<(threads + 255) / 256, 256, 0, stream>>>(rowptr, edgesrc, Bt, A, N);
    }

    // layer 2: T3 = h@W2root^T + b2, T2 = h@W2rel^T
    {
        constexpr int TILE = 64 * 4;
        int grid = (N + TILE - 1) / TILE;
        gemm_dual<64, 16, 16, 64, 4><<<grid, 512, 0, stream>>>(A, N, W2ROOT, W2REL, B2, T3, T2);
    }

    // out = log_softmax(t3 + gather(t2))
    {
        int threads = N * 4;
        gather_lsm<<<(threads + 255) / 256, 256, 0, stream>>>(rowptr, edgesrc, T3, T2, OUT, N);
    }
}

// Round 4
// 202.707 us; speedup vs baseline: 3.9662x; 1.1027x over previous
//
#include <hip/hip_runtime.h>
#include <math.h>

constexpr int CIN = 128, CHID = 64, COUT = 16;

// ---------------------------------------------------------------------------
// Edge-index dtype detection: if input is raw int64 (little-endian, values
// < 2^31), every odd int32 word is 0.
// ---------------------------------------------------------------------------
__global__ void detect_kernel(const int* __restrict__ e, int* __restrict__ flag) {
    int v = e[2 * threadIdx.x + 1];
    unsigned long long b = __ballot(v == 0);
    if (threadIdx.x == 0) flag[0] = (b == 0xFFFFFFFFFFFFFFFFULL) ? 1 : 0;
}

// convert to int32 src/dst + histogram of dst (int atomics)
__global__ void convert_hist(const int* __restrict__ e, int E,
                             const int* __restrict__ flag,
                             int* __restrict__ srcI, int* __restrict__ dstI,
                             int* __restrict__ counts) {
    int is64 = flag[0];
    int stride = gridDim.x * blockDim.x;
    for (int t = blockIdx.x * blockDim.x + threadIdx.x; t < E; t += stride) {
        int s, d;
        if (is64) { s = e[2 * t]; d = e[2 * (E + t)]; }
        else      { s = e[t];     d = e[E + t];       }
        srcI[t] = s;
        dstI[t] = d;
        atomicAdd(&counts[d], 1);
    }
}

// ---------------------------------------------------------------------------
// Multi-block exclusive scan of counts[N] -> rowptr[N+1] (+ cursor copy).
// ---------------------------------------------------------------------------
__global__ __launch_bounds__(256)
void scan_partials(const int* __restrict__ counts, int N, int* __restrict__ blocksum) {
    __shared__ int red[256];
    const int tid = threadIdx.x;
    const int base = blockIdx.x * 1024 + tid * 4;
    int s = 0;
#pragma unroll
    for (int i = 0; i < 4; ++i) {
        int idx = base + i;
        if (idx < N) s += counts[idx];
    }
    red[tid] = s;
    __syncthreads();
    for (int d = 128; d > 0; d >>= 1) {
        if (tid < d) red[tid] += red[tid + d];
        __syncthreads();
    }
    if (tid == 0) blocksum[blockIdx.x] = red[0];
}

__global__ __launch_bounds__(1024)
void scan_blocksums(const int* __restrict__ blocksum, int NB, int* __restrict__ blockoff) {
    __shared__ int part[1024];
    const int tid = threadIdx.x;
    part[tid] = (tid < NB) ? blocksum[tid] : 0;
    __syncthreads();
    for (int d = 1; d < 1024; d <<= 1) {
        int v = (tid >= d) ? part[tid - d] : 0;
        __syncthreads();
        part[tid] += v;
        __syncthreads();
    }
    if (tid < NB) blockoff[tid] = (tid == 0) ? 0 : part[tid - 1];
}

__global__ __launch_bounds__(256)
void scan_apply(const int* __restrict__ counts, int N, const int* __restrict__ blockoff,
                int* __restrict__ rowptr, int* __restrict__ cursor) {
    __shared__ int part[256];
    const int tid = threadIdx.x;
    const int base = blockIdx.x * 1024 + tid * 4;
    int c[4];
    int s = 0;
#pragma unroll
    for (int i = 0; i < 4; ++i) {
        int idx = base + i;
        c[i] = (idx < N) ? counts[idx] : 0;
        s += c[i];
    }
    part[tid] = s;
    __syncthreads();
    for (int d = 1; d < 256; d <<= 1) {
        int v = (tid >= d) ? part[tid - d] : 0;
        __syncthreads();
        part[tid] += v;
        __syncthreads();
    }
    int prefix = blockoff[blockIdx.x] + ((tid == 0) ? 0 : part[tid - 1]);
#pragma unroll
    for (int i = 0; i < 4; ++i) {
        int idx = base + i;
        if (idx < N) {
            rowptr[idx] = prefix;
            cursor[idx] = prefix;
            prefix += c[i];
            if (idx == N - 1) rowptr[N] = prefix;
        }
    }
}

// bucket-fill: edgesrc grouped by dst
__global__ void fill_kernel(const int* __restrict__ srcI, const int* __restrict__ dstI,
                            int E, int* __restrict__ cursor, int* __restrict__ edgesrc) {
    int stride = gridDim.x * blockDim.x;
    for (int t = blockIdx.x * blockDim.x + threadIdx.x; t < E; t += stride) {
        int p = atomicAdd(&cursor[dstI[t]], 1);
        edgesrc[p] = srcI[t];
    }
}

// ---------------------------------------------------------------------------
// Dual-output GEMM, K-tiled LDS staging (KT-slice loop keeps LDS ~25 KB so
// 3+ blocks/CU fit; the old full-K staging was 113 KB -> 1 block/CU).
// Da = X·Wa^T + bias ; Db = X·Wb^T
// ---------------------------------------------------------------------------
template<int K, int KT, int OA, int OB, int NSLOT, int T>
__global__ __launch_bounds__(512, 6)
void gemm_dual(const float* __restrict__ X, int N,
               const float* __restrict__ Wa, const float* __restrict__ Wb,
               const float* __restrict__ bias,
               float* __restrict__ Da, float* __restrict__ Db) {
    constexpr int O = OA + OB;
    constexpr int OG = O / 4;
    constexpr int TILE = NSLOT * T;
    constexpr int PADKT = KT + 4;
    constexpr int BLOCK = OG * NSLOT;
    static_assert(BLOCK == 512, "block size mismatch");

    __shared__ float wT[KT * O];          // k-major weight slice
    __shared__ float xs[TILE * PADKT];    // x slice, rows padded
    const int tid = threadIdx.x;

    const int og = tid % OG;
    const int slot = tid / OG;
    const int o4 = og * 4;
    float4 bv = make_float4(0.f, 0.f, 0.f, 0.f);
    if (o4 < OA) bv = *(const float4*)&bias[o4];

    const int n0 = blockIdx.x * TILE;

    float4 acc[T];
#pragma unroll
    for (int i = 0; i < T; ++i) acc[i] = make_float4(0.f, 0.f, 0.f, 0.f);

    for (int kt = 0; kt < K; kt += KT) {
        // stage weight slice (k-major)
        for (int i4 = tid; i4 < OA * (KT / 4); i4 += BLOCK) {
            int o = i4 % OA, kq = i4 / OA;
            float4 v = *(const float4*)&Wa[o * K + kt + kq * 4];
            wT[(4 * kq + 0) * O + o] = v.x;
            wT[(4 * kq + 1) * O + o] = v.y;
            wT[(4 * kq + 2) * O + o] = v.z;
            wT[(4 * kq + 3) * O + o] = v.w;
        }
        for (int i4 = tid; i4 < OB * (KT / 4); i4 += BLOCK) {
            int o = i4 % OB, kq = i4 / OB;
            float4 v = *(const float4*)&Wb[o * K + kt + kq * 4];
            wT[(4 * kq + 0) * O + OA + o] = v.x;
            wT[(4 * kq + 1) * O + OA + o] = v.y;
            wT[(4 * kq + 2) * O + OA + o] = v.z;
            wT[(4 * kq + 3) * O + OA + o] = v.w;
        }
        // stage x slice (coalesced float4)
        for (int i4 = tid; i4 < TILE * (KT / 4); i4 += BLOCK) {
            int node = i4 / (KT / 4), kq = i4 % (KT / 4);
            int n = n0 + node;
            float4 v = make_float4(0.f, 0.f, 0.f, 0.f);
            if (n < N) v = *(const float4*)&X[(size_t)n * K + kt + kq * 4];
            *(float4*)&xs[node * PADKT + kq * 4] = v;
        }
        __syncthreads();

        const float* xrow = &xs[slot * T * PADKT];
#pragma unroll 8
        for (int k = 0; k < KT; ++k) {
            float4 w4 = *(const float4*)&wT[k * O + o4];
#pragma unroll
            for (int i = 0; i < T; ++i) {
                float xv = xrow[i * PADKT + k];
                acc[i].x = fmaf(xv, w4.x, acc[i].x);
                acc[i].y = fmaf(xv, w4.y, acc[i].y);
                acc[i].z = fmaf(xv, w4.z, acc[i].z);
                acc[i].w = fmaf(xv, w4.w, acc[i].w);
            }
        }
        __syncthreads();
    }

#pragma unroll
    for (int i = 0; i < T; ++i) {
        int n = n0 + slot * T + i;
        if (n >= N) continue;
        float4 r = acc[i];
        if (o4 < OA) {
            r.x += bv.x; r.y += bv.y; r.z += bv.z; r.w += bv.w;
            *(float4*)&Da[(size_t)n * OA + o4] = r;
        } else {
            *(float4*)&Db[(size_t)n * OB + (o4 - OA)] = r;
        }
    }
}

// ---------------------------------------------------------------------------
// CSR gather + fused relu(t0 + agg), in place over A.
// ---------------------------------------------------------------------------
__global__ void gather_relu64(const int* __restrict__ rowptr, const int* __restrict__ edgesrc,
                              const float* __restrict__ T1, float* __restrict__ A, int N) {
    constexpr int F = 64, Q = F / 4;
    int idx = blockIdx.x * blockDim.x + threadIdx.x;
    int n = idx / Q, q = idx % Q;
    if (n >= N) return;
    int beg = rowptr[n], end = rowptr[n + 1];
    float4 acc = make_float4(0.f, 0.f, 0.f, 0.f);
    for (int j = beg; j < end; ++j) {
        int s = edgesrc[j];
        float4 v = *(const float4*)&T1[(size_t)s * F + q * 4];
        acc.x += v.x; acc.y += v.y; acc.z += v.z; acc.w += v.w;
    }
    float4 a = *(const float4*)&A[(size_t)n * F + q * 4];
    a.x = fmaxf(a.x + acc.x, 0.f);
    a.y = fmaxf(a.y + acc.y, 0.f);
    a.z = fmaxf(a.z + acc.z, 0.f);
    a.w = fmaxf(a.w + acc.w, 0.f);
    *(float4*)&A[(size_t)n * F + q * 4] = a;
}

// ---------------------------------------------------------------------------
// CSR gather of t2 (width 16) + fused log_softmax(t3 + agg).
// ---------------------------------------------------------------------------
__global__ void gather_lsm(const int* __restrict__ rowptr, const int* __restrict__ edgesrc,
                           const float* __restrict__ T3, const float* __restrict__ T2,
                           float* __restrict__ out, int N) {
    int idx = blockIdx.x * blockDim.x + threadIdx.x;
    int n = idx / 4, c = idx % 4;
    if (n >= N) return;
    int beg = rowptr[n], end = rowptr[n + 1];
    float4 acc = make_float4(0.f, 0.f, 0.f, 0.f);
    for (int j = beg; j < end; ++j) {
        int s = edgesrc[j];
        float4 v = *(const float4*)&T2[(size_t)s * 16 + c * 4];
        acc.x += v.x; acc.y += v.y; acc.z += v.z; acc.w += v.w;
    }
    float4 t = *(const float4*)&T3[(size_t)n * 16 + c * 4];
    float4 v = make_float4(t.x + acc.x, t.y + acc.y, t.z + acc.z, t.w + acc.w);
    float m = fmaxf(fmaxf(v.x, v.y), fmaxf(v.z, v.w));
    for (int d = 1; d < 4; d <<= 1) m = fmaxf(m, __shfl_xor(m, d, 4));
    float s = expf(v.x - m) + expf(v.y - m) + expf(v.z - m) + expf(v.w - m);
    for (int d = 1; d < 4; d <<= 1) s += __shfl_xor(s, d, 4);
    float ls = m + logf(s);
    float4 r = make_float4(v.x - ls, v.y - ls, v.z - ls, v.w - ls);
    *(float4*)&out[(size_t)n * 16 + c * 4] = r;
}

extern "C" void kernel_launch(void* const* d_in, const int* in_sizes, int n_in,
                              void* d_out, int out_size, void* d_ws, size_t ws_size,
                              hipStream_t stream) {
    const float* X      = (const float*)d_in[0];
    const int*   EIDX   = (const int*)d_in[1];
    const float* W1REL  = (const float*)d_in[2];
    const float* W1ROOT = (const float*)d_in[3];
    const float* B1     = (const float*)d_in[4];
    const float* W2REL  = (const float*)d_in[5];
    const float* W2ROOT = (const float*)d_in[6];
    const float* B2     = (const float*)d_in[7];
    float* OUT = (float*)d_out;

    const int N = in_sizes[0] / CIN;   // 100000
    const int E = in_sizes[1] / 2;     // 640000
    const int NB = (N + 1023) / 1024;  // scan blocks

    char* wsb = (char*)d_ws;
    size_t off = 0;
    auto alloc = [&](size_t bytes) { void* p = wsb + off; off += (bytes + 255) & ~size_t(255); return p; };

    int* flag     = (int*)alloc(256);
    int* srcI     = (int*)alloc((size_t)E * 4);
    int* dstI     = (int*)alloc((size_t)E * 4);
    int* edgesrc  = (int*)alloc((size_t)E * 4);
    int* counts   = (int*)alloc((size_t)N * 4);
    int* rowptr   = (int*)alloc((size_t)(N + 1) * 4);
    int* cursor   = (int*)alloc((size_t)N * 4);
    int* blocksum = (int*)alloc((size_t)NB * 4);
    int* blockoff = (int*)alloc((size_t)NB * 4);
    float* A      = (float*)alloc((size_t)N * CHID * 4);  // t0 -> h (in place)
    float* Bt     = (float*)alloc((size_t)N * CHID * 4);  // t1, then t3|t2
    if (off > ws_size) return;

    float* T3 = Bt;                      // [N,16]
    float* T2 = Bt + (size_t)N * COUT;   // [N,16]

    hipMemsetAsync(counts, 0, (size_t)N * 4, stream);

    detect_kernel<<<1, 64, 0, stream>>>(EIDX, flag);
    convert_hist<<<1024, 256, 0, stream>>>(EIDX, E, flag, srcI, dstI, counts);
    scan_partials<<<NB, 256, 0, stream>>>(counts, N, blocksum);
    scan_blocksums<<<1, 1024, 0, stream>>>(blocksum, NB, blockoff);
    scan_apply<<<NB, 256, 0, stream>>>(counts, N, blockoff, rowptr, cursor);
    fill_kernel<<<1024, 256, 0, stream>>>(srcI, dstI, E, cursor, edgesrc);

    // layer 1: A = X@W1root^T + b1, Bt = X@W1rel^T   (K=128, KT=32, TILE=64)
    {
        constexpr int TILE = 16 * 4;
        int grid = (N + TILE - 1) / TILE;
        gemm_dual<128, 32, 64, 64, 16, 4><<<grid, 512, 0, stream>>>(X, N, W1ROOT, W1REL, B1, A, Bt);
    }

    // h = relu(t0 + gather(t1))  [in place over A]
    {
        int threads = N * 16;
        gather_relu64<<<(threads + 255) / 256, 256, 0, stream>>>(rowptr, edgesrc, Bt, A, N);
    }

    // layer 2: T3 = h@W2root^T + b2, T2 = h@W2rel^T   (K=64, KT=32, TILE=128)
    {
        constexpr int TILE = 64 * 2;
        int grid = (N + TILE - 1) / TILE;
        gemm_dual<64, 32, 16, 16, 64, 2><<<grid, 512, 0, stream>>>(A, N, W2ROOT, W2REL, B2, T3, T2);
    }

    // out = log_softmax(t3 + gather(t2))
    {
        int threads = N * 4;
        gather_lsm<<<(threads + 255) / 256, 256, 0, stream>>>(rowptr, edgesrc, T3, T2, OUT, N);
    }
}